// Round 7
// baseline (12204.675 us; speedup 1.0000x reference)
//
#include <hip/hip_runtime.h>
#include <float.h>

// FPS: N=524288 pts, M=2048 selected (idx[0]=0), out = pos[idxs] (2048x3 f32).
// 64 cooperative blocks x 512 threads. R4 structure minus the intra-block LDS
// reduce: each of the block's 8 waves publishes its wave-best DIRECTLY to a
// dense per-wave word buf[blk*8+wav]. 512 words = 64 lines; each line's 8
// writers are the waves of ONE block (one CU) -> no cross-XCD store sharing
// (R3's poison). Poll reads are dense/coalesced: 8 x 512B loads = 4 KB/round
// (R6's padded poll was 32 KB/round -> FETCH blowup). No LDS, no
// __syncthreads anywhere in the loop.

#define NPTS     524288
#define MOUT     2048
#define NBLK     64
#define NTHR     512
#define NWAVE    (NTHR / 64)            // 8
#define GTHREADS (NBLK * NTHR)          // 32768
#define PPT      (NPTS / GTHREADS)      // 16
#define NSLOT    (NBLK * NWAVE)         // 512 words, dense
#define KPL      (NSLOT / 64)           // 8 words polled per lane
#define MASK51   ((1ull << 51) - 1)

// word: [tag:13][fbits:32][idx_inv:19]
// fbits = IEEE bits of min_d (>=0 so bit order == value order)
// idx_inv = (NPTS-1)-idx: equal values -> smaller idx wins the max
// => first-occurrence tie-break == jnp.argmax (absmax 0.0 in R1-R6).
// Wave bests are globally unique 64-bit words (point ownership partitioned)
// => winner lane identified by word equality (exactly one match).

__global__ void __launch_bounds__(NTHR, 1) fps_kernel(
    const float* __restrict__ pos, float* __restrict__ out,
    unsigned long long* __restrict__ slots)
{
    const unsigned tid  = threadIdx.x;
    const unsigned lane = tid & 63u;
    const unsigned wav  = tid >> 6;
    const unsigned blk  = blockIdx.x;
    const unsigned wid  = blk * NWAVE + wav;      // dense word index, 0..511
    const unsigned g    = blk * NTHR + tid;

    float X[PPT], Y[PPT], Z[PPT], D[PPT];
#pragma unroll
    for (int p = 0; p < PPT; ++p) {
        const unsigned idx = g + (unsigned)p * GTHREADS;
        X[p] = pos[3u * idx + 0];
        Y[p] = pos[3u * idx + 1];
        Z[p] = pos[3u * idx + 2];
        D[p] = FLT_MAX;
    }

    float px = pos[0], py = pos[1], pz = pos[2];
    if (g == 0) { out[0] = px; out[1] = py; out[2] = pz; }

    for (int i = 1; i < MOUT; ++i) {
        const unsigned p2 = (unsigned)i & 1u;
        // ---- distance update + per-thread argmax (exact fp32: no FMA,
        // ---- sum order (dx^2+dy^2)+dz^2; absmax==0 verified R1-R6) ----
        float bv = -1.0f;
        unsigned bi = 0;
#pragma unroll
        for (int p = 0; p < PPT; ++p) {
            float dx = __fsub_rn(X[p], px);
            float dy = __fsub_rn(Y[p], py);
            float dz = __fsub_rn(Z[p], pz);
            float d  = __fadd_rn(__fadd_rn(__fmul_rn(dx, dx), __fmul_rn(dy, dy)),
                                 __fmul_rn(dz, dz));
            float m  = fminf(D[p], d);
            D[p] = m;
            if (m > bv) { bv = m; bi = g + (unsigned)p * GTHREADS; }
        }
        unsigned long long best =
            ((unsigned long long)__float_as_uint(bv) << 19) |
            (unsigned long long)((NPTS - 1u) - bi);

        // ---- wave butterfly: all lanes get wave best ----
#pragma unroll
        for (int off = 32; off > 0; off >>= 1) {
            unsigned long long o = __shfl_xor(best, off, 64);
            if (o > best) best = o;
        }

        // ---- publish wave best directly (no intra-block reduce) ----
        const unsigned long long tag = (unsigned long long)i;
        unsigned long long* buf = slots + p2 * NSLOT;
        if (lane == 0)
            __hip_atomic_store(&buf[wid], (tag << 51) | best,
                               __ATOMIC_RELAXED, __HIP_MEMORY_SCOPE_AGENT);

        // ---- poll all 512 dense words: 8 coalesced 512B loads in flight ----
        unsigned long long v[KPL];
        for (;;) {
            bool ok = true;
#pragma unroll
            for (int k = 0; k < KPL; ++k)
                v[k] = __hip_atomic_load(&buf[lane + (unsigned)k * 64u],
                                         __ATOMIC_RELAXED, __HIP_MEMORY_SCOPE_AGENT);
#pragma unroll
            for (int k = 0; k < KPL; ++k) ok &= ((v[k] >> 51) == tag);
            if (__all(ok)) break;
            __builtin_amdgcn_s_sleep(1);
        }

        // ---- per-lane reduce of its 8 candidates ----
        unsigned long long c = v[0] & MASK51;
#pragma unroll
        for (int k = 1; k < KPL; ++k) {
            unsigned long long w = v[k] & MASK51;
            if (w > c) c = w;
        }
        // prefetch this lane's candidate coords; loads fly during butterfly
        unsigned cidx = (NPTS - 1u) - (unsigned)(c & 0x7FFFFull);
        float cx = pos[3u * cidx + 0];
        float cy = pos[3u * cidx + 1];
        float cz = pos[3u * cidx + 2];

        unsigned long long win = c;
#pragma unroll
        for (int off = 32; off > 0; off >>= 1) {
            unsigned long long o = __shfl_xor(win, off, 64);
            if (o > win) win = o;
        }
        unsigned long long bal = __ballot(win == c);   // exactly one lane matches
        int src = __ffsll(bal) - 1;
        px = __shfl(cx, src, 64);
        py = __shfl(cy, src, 64);
        pz = __shfl(cz, src, 64);

        if (g == 0) {
            out[3 * i + 0] = px; out[3 * i + 1] = py; out[3 * i + 2] = pz;
        }
    }
}

extern "C" void kernel_launch(void* const* d_in, const int* in_sizes, int n_in,
                              void* d_out, int out_size, void* d_ws, size_t ws_size,
                              hipStream_t stream) {
    const float* pos = (const float*)d_in[0];
    float* out = (float*)d_out;
    unsigned long long* slots = (unsigned long long*)d_ws;  // 2 x 512 x 8B = 8 KB
    // No memset: d_ws re-poisoned 0xAA each launch; poison decodes to tag
    // 0x1555, never a real tag (1..2047). Monotone tags + parity kill ABA.

    void* args[] = { (void*)&pos, (void*)&out, (void*)&slots };
    hipLaunchCooperativeKernel((void*)fps_kernel, dim3(NBLK), dim3(NTHR),
                               args, 0, stream);
}

// Round 9
// 5297.632 us; speedup vs baseline: 2.3038x; 2.3038x over previous
//
#include <hip/hip_runtime.h>
#include <float.h>

// FPS: N=524288 pts, M=2048 selected (idx[0]=0), out = pos[idxs] (2048x3 f32).
// 128 cooperative blocks x 256 threads (PPT=16, 2 waves/SIMD on 128 CUs).
// Exchange law learned R3-R7: cost ~ #global publish events + poll footprint.
// So: ONE aggregated publish per block (128 events), poll footprint 128 lines.
// Intra-block aggregation is barrier-free: monotone-tagged LDS atomicMax
// (tag in top bits -> iteration i+1 words dominate i; NO reset needed) +
// monotone arrival counter; the last-finishing wave publishes immediately.
// No __syncthreads in the loop. Poll: all waves, 2 loads/lane, padded slots.
//
// (Resubmission of R8 — container infra flake, no dispatch evidence. Logic
// re-audited: arrival counter gives exactly one r==4i-1 per iteration; a wave
// reaches iter i+1 only after its block published i, so no cross-iteration
// LDS-max pollution; parity ABA impossible: publishing i+2 requires all
// blocks past poll(i).)

#define NPTS     524288
#define MOUT     2048
#define NBLK     128
#define NTHR     256
#define NWAVE    (NTHR / 64)            // 4
#define GTHREADS (NBLK * NTHR)          // 32768
#define PPT      (NPTS / GTHREADS)      // 16
#define SLOT_STRIDE 8                   // u64 stride -> own 64 B line per block
#define KPL      (NBLK / 64)            // 2 slots polled per lane
#define MASK51   ((1ull << 51) - 1)

// word: [tag:13][fbits:32][idx_inv:19]
// fbits = IEEE bits of min_d (>=0 so bit order == value order)
// idx_inv = (NPTS-1)-idx: equal values -> smaller idx wins the max
// => first-occurrence tie-break == jnp.argmax (absmax 0.0 in R1-R7).
// Tag occupies the TOP bits => words are monotone in iteration, which makes
// both the LDS max accumulator and the global slots reset-free.
// Block bests are globally unique => winner lane found by word equality.

__global__ void __launch_bounds__(NTHR, 1) fps_kernel(
    const float* __restrict__ pos, float* __restrict__ out,
    unsigned long long* __restrict__ slots)
{
    const unsigned tid  = threadIdx.x;
    const unsigned lane = tid & 63u;
    const unsigned blk  = blockIdx.x;
    const unsigned g    = blk * NTHR + tid;

    float X[PPT], Y[PPT], Z[PPT], D[PPT];
#pragma unroll
    for (int p = 0; p < PPT; ++p) {
        const unsigned idx = g + (unsigned)p * GTHREADS;
        X[p] = pos[3u * idx + 0];
        Y[p] = pos[3u * idx + 1];
        Z[p] = pos[3u * idx + 2];
        D[p] = FLT_MAX;
    }

    float px = pos[0], py = pos[1], pz = pos[2];
    if (g == 0) { out[0] = px; out[1] = py; out[2] = pz; }

    __shared__ unsigned long long smax;   // monotone tagged max, never reset
    __shared__ unsigned scnt;             // monotone arrival counter
    if (tid == 0) { smax = 0ull; scnt = 0u; }
    __syncthreads();                      // once, outside the loop

    for (int i = 1; i < MOUT; ++i) {
        const unsigned p2 = (unsigned)i & 1u;
        // ---- distance update + per-thread argmax (exact fp32: no FMA,
        // ---- sum order (dx^2+dy^2)+dz^2; absmax==0 verified R1-R7) ----
        float bv = -1.0f;
        unsigned bi = 0;
#pragma unroll
        for (int p = 0; p < PPT; ++p) {
            float dx = __fsub_rn(X[p], px);
            float dy = __fsub_rn(Y[p], py);
            float dz = __fsub_rn(Z[p], pz);
            float d  = __fadd_rn(__fadd_rn(__fmul_rn(dx, dx), __fmul_rn(dy, dy)),
                                 __fmul_rn(dz, dz));
            float m  = fminf(D[p], d);
            D[p] = m;
            if (m > bv) { bv = m; bi = g + (unsigned)p * GTHREADS; }
        }
        const unsigned long long tag = (unsigned long long)i;
        unsigned long long best =
            ((unsigned long long)__float_as_uint(bv) << 19) |
            (unsigned long long)((NPTS - 1u) - bi);

        // ---- wave butterfly: all lanes get wave best ----
#pragma unroll
        for (int off = 32; off > 0; off >>= 1) {
            unsigned long long o = __shfl_xor(best, off, 64);
            if (o > best) best = o;
        }

        // ---- barrier-free block aggregation: max then arrive; the wave
        // ---- whose arrival completes the set publishes immediately ----
        unsigned long long* buf = slots + p2 * (NBLK * SLOT_STRIDE);
        if (lane == 0) {
            atomicMax(&smax, (tag << 51) | best);     // LDS, in-order per wave
            unsigned r = atomicAdd(&scnt, 1u);
            if (r == (unsigned)NWAVE * (unsigned)i - 1u) {   // last finisher
                unsigned long long m =
                    __hip_atomic_load(&smax, __ATOMIC_RELAXED,
                                      __HIP_MEMORY_SCOPE_WORKGROUP);
                __hip_atomic_store(&buf[blk * SLOT_STRIDE], m,
                                   __ATOMIC_RELAXED, __HIP_MEMORY_SCOPE_AGENT);
            }
        }

        // ---- all waves poll the 128 padded slots (2 loads/lane) ----
        unsigned long long v[KPL];
        for (;;) {
            bool ok = true;
#pragma unroll
            for (int k = 0; k < KPL; ++k)
                v[k] = __hip_atomic_load(&buf[(lane + (unsigned)k * 64u) * SLOT_STRIDE],
                                         __ATOMIC_RELAXED, __HIP_MEMORY_SCOPE_AGENT);
#pragma unroll
            for (int k = 0; k < KPL; ++k) ok &= ((v[k] >> 51) == tag);
            if (__all(ok)) break;
            __builtin_amdgcn_s_sleep(1);
        }

        // ---- per-lane reduce + prefetched-coords ballot broadcast ----
        unsigned long long c = v[0] & MASK51;
#pragma unroll
        for (int k = 1; k < KPL; ++k) {
            unsigned long long w = v[k] & MASK51;
            if (w > c) c = w;
        }
        unsigned cidx = (NPTS - 1u) - (unsigned)(c & 0x7FFFFull);
        float cx = pos[3u * cidx + 0];
        float cy = pos[3u * cidx + 1];
        float cz = pos[3u * cidx + 2];

        unsigned long long win = c;
#pragma unroll
        for (int off = 32; off > 0; off >>= 1) {
            unsigned long long o = __shfl_xor(win, off, 64);
            if (o > win) win = o;
        }
        unsigned long long bal = __ballot(win == c);   // exactly one lane matches
        int src = __ffsll(bal) - 1;
        px = __shfl(cx, src, 64);
        py = __shfl(cy, src, 64);
        pz = __shfl(cz, src, 64);

        if (g == 0) {
            out[3 * i + 0] = px; out[3 * i + 1] = py; out[3 * i + 2] = pz;
        }
    }
}

extern "C" void kernel_launch(void* const* d_in, const int* in_sizes, int n_in,
                              void* d_out, int out_size, void* d_ws, size_t ws_size,
                              hipStream_t stream) {
    const float* pos = (const float*)d_in[0];
    float* out = (float*)d_out;
    unsigned long long* slots = (unsigned long long*)d_ws;  // 2 x 128 x 64B = 16 KB
    // No memset: d_ws re-poisoned 0xAA each launch; poison decodes to tag
    // 0x1555, never a real tag (1..2047). Monotone tags + parity kill ABA.

    void* args[] = { (void*)&pos, (void*)&out, (void*)&slots };
    hipLaunchCooperativeKernel((void*)fps_kernel, dim3(NBLK), dim3(NTHR),
                               args, 0, stream);
}